// Round 12
// baseline (245.486 us; speedup 1.0000x reference)
//
#include <hip/hip_runtime.h>
#include <math.h>

#define BB 16
#define TT 24
#define NN 128
#define DD 64
#define PTOT (BB * TT * NN)   // 49152 positions
#define P64  (PTOT * 64)      // elements per (B,T,N,64) buffer

typedef __attribute__((ext_vector_type(8))) short bf16x8;
typedef __attribute__((ext_vector_type(4))) float f32x4;

__device__ __forceinline__ unsigned short f2bf(float f) {
    unsigned u = __builtin_bit_cast(unsigned, f);
    u = (u + 0x7fffu + ((u >> 16) & 1u)) >> 16;   // round-to-nearest-even
    return (unsigned short)u;
}
__device__ __forceinline__ void unpack8(uint4 u, float* f) {
    f[0] = __builtin_bit_cast(float, u.x << 16);
    f[1] = __builtin_bit_cast(float, u.x & 0xFFFF0000u);
    f[2] = __builtin_bit_cast(float, u.y << 16);
    f[3] = __builtin_bit_cast(float, u.y & 0xFFFF0000u);
    f[4] = __builtin_bit_cast(float, u.z << 16);
    f[5] = __builtin_bit_cast(float, u.z & 0xFFFF0000u);
    f[6] = __builtin_bit_cast(float, u.w << 16);
    f[7] = __builtin_bit_cast(float, u.w & 0xFFFF0000u);
}
__device__ __forceinline__ uint4 pack8(const float* f) {
    uint4 o;
    o.x = (unsigned)f2bf(f[0]) | ((unsigned)f2bf(f[1]) << 16);
    o.y = (unsigned)f2bf(f[2]) | ((unsigned)f2bf(f[3]) << 16);
    o.z = (unsigned)f2bf(f[4]) | ((unsigned)f2bf(f[5]) << 16);
    o.w = (unsigned)f2bf(f[6]) | ((unsigned)f2bf(f[7]) << 16);
    return o;
}

// ---------------------------------------------------------------------------
// Kernel 0: combined weight prep.
// blocks 0..287: 6 proj weights (192x64) -> bf16 [j][n][k]  (Wt)
// blocks 288..415: 8 epi weights (64x64) -> bf16 [mat][n][k] (Wt8)
// ---------------------------------------------------------------------------
__global__ __launch_bounds__(256) void wprep_all(
    const float* __restrict__ W0, const float* __restrict__ W1,
    const float* __restrict__ W2, const float* __restrict__ W3,
    const float* __restrict__ W4, const float* __restrict__ W5,
    const float* __restrict__ E0, const float* __restrict__ E1,
    const float* __restrict__ E2, const float* __restrict__ E3,
    const float* __restrict__ E4, const float* __restrict__ E5,
    const float* __restrict__ E6, const float* __restrict__ E7,
    unsigned short* __restrict__ Wt, unsigned short* __restrict__ Wt8)
{
    const int bid = blockIdx.x;
    if (bid < 288) {
        const float* Ws[6] = {W0, W1, W2, W3, W4, W5};
        const int e = bid * 256 + threadIdx.x;          // < 73728
        const int j = e / 12288;
        const int r = e % 12288;
        const int k = r / 64;
        const int n = r % 64;
        Wt[j * 12288 + n * 192 + k] = f2bf(Ws[j][k * 64 + n]);
    } else {
        const float* Es[8] = {E0, E1, E2, E3, E4, E5, E6, E7};
        const int e = (bid - 288) * 256 + threadIdx.x;  // < 32768
        const int mat = e >> 12;
        const int r = e & 4095;
        const int k = r >> 6;
        const int n = r & 63;
        Wt8[mat * 4096 + n * 64 + k] = f2bf(Es[mat][k * 64 + n]);
    }
}

// ---------------------------------------------------------------------------
// Kernel 1: fused 6-way QKV projection via bf16 MFMA (proven structure).
// Block = 256 thr (4 waves), 64-position tile.  Grid = PTOT/64 = 768.
// XE^T frags cached in VGPRs, weights streamed once per (j,nt) tile.
// Outputs (bf16):
//   spatial  (j<3): [bt][head][n][8]  (fully coalesced per wave)
//   temporal (j>=3): [pos][ch]        (fully coalesced; tattn does the
//                                      strided reads instead — reads scatter
//                                      is far cheaper than store scatter)
// ---------------------------------------------------------------------------
__global__ __launch_bounds__(256) void proj_kernel(
    const float* __restrict__ X, const float* __restrict__ TLE,
    const unsigned short* __restrict__ Wt,   // [6][64][192] bf16
    const float* __restrict__ b0, const float* __restrict__ b1,
    const float* __restrict__ b2, const float* __restrict__ b3,
    const float* __restrict__ b4, const float* __restrict__ b5,
    unsigned short* __restrict__ qs, unsigned short* __restrict__ ks,
    unsigned short* __restrict__ vs,
    unsigned short* __restrict__ qt, unsigned short* __restrict__ kt,
    unsigned short* __restrict__ vt)
{
    __shared__ __align__(16) unsigned short xe[64][200];  // [m][k] bf16
    const int tid = threadIdx.x;
    const long p0 = (long)blockIdx.x * 64;

    #pragma unroll
    for (int i = 0; i < 12; ++i) {                 // 64*48 float4s / 256 thr
        const int idx4 = tid + i * 256;
        const int m  = idx4 / 48;
        const int kq = idx4 % 48;
        const int k  = kq * 4;
        float4 v;
        if (k < 64) v = *reinterpret_cast<const float4*>(X + (p0 + m) * 64 + k);
        else        v = *reinterpret_cast<const float4*>(TLE + (p0 + m) * 128 + (k - 64));
        ushort4 pk;
        pk.x = f2bf(v.x); pk.y = f2bf(v.y); pk.z = f2bf(v.z); pk.w = f2bf(v.w);
        *reinterpret_cast<ushort4*>(&xe[m][k]) = pk;
    }
    __syncthreads();

    const int w    = tid >> 6;
    const int l    = tid & 63;
    const int quad = l >> 4;
    const int l16  = l & 15;

    bf16x8 xef[4][6];
    #pragma unroll
    for (int mt = 0; mt < 4; ++mt)
        #pragma unroll
        for (int kc = 0; kc < 6; ++kc)
            xef[mt][kc] = *reinterpret_cast<const bf16x8*>(
                &xe[mt * 16 + l16][kc * 32 + quad * 8]);

    const float* bs[6] = {b0, b1, b2, b3, b4, b5};
    unsigned short* Os[6] = {qs, ks, vs, qt, kt, vt};

    const int bt = blockIdx.x >> 1;          // (b,t) index
    const int nh = (blockIdx.x & 1) * 64;    // n offset within (b,t)

    #pragma unroll
    for (int q6 = 0; q6 < 6; ++q6) {
        const int tile = w * 6 + q6;
        const int j  = tile >> 2;            // matrix 0..5 (wave-uniform)
        const int nt = tile & 3;             // channel tile
        const unsigned short* __restrict__ Wj = Wt + j * 12288;

        bf16x8 wf[6];
        #pragma unroll
        for (int kc = 0; kc < 6; ++kc)
            wf[kc] = *reinterpret_cast<const bf16x8*>(
                &Wj[(nt * 16 + l16) * 192 + kc * 32 + quad * 8]);

        f32x4 acc[4];
        #pragma unroll
        for (int mt = 0; mt < 4; ++mt) acc[mt] = (f32x4){0.f, 0.f, 0.f, 0.f};

        #pragma unroll
        for (int kc = 0; kc < 6; ++kc)
            #pragma unroll
            for (int mt = 0; mt < 4; ++mt)
                acc[mt] = __builtin_amdgcn_mfma_f32_16x16x32_bf16(
                    wf[kc], xef[mt][kc], acc[mt], 0, 0, 0);

        const int ch0 = nt * 16 + quad * 4;  // 4 consecutive channels
        const float4 b4 = *reinterpret_cast<const float4*>(&bs[j][ch0]);
        unsigned short* __restrict__ Oj = Os[j];

        #pragma unroll
        for (int mt = 0; mt < 4; ++mt) {
            const int pos = mt * 16 + l16;
            ushort4 pk;
            pk.x = f2bf(fmaxf(acc[mt][0] + b4.x, 0.0f));
            pk.y = f2bf(fmaxf(acc[mt][1] + b4.y, 0.0f));
            pk.z = f2bf(fmaxf(acc[mt][2] + b4.z, 0.0f));
            pk.w = f2bf(fmaxf(acc[mt][3] + b4.w, 0.0f));
            if (j < 3) {
                // spatial: [bt][h][n][8] — wave covers 2 contiguous 256B spans
                const int n = nh + pos;
                *reinterpret_cast<ushort4*>(
                    &Oj[(long)bt * 8192 + (ch0 >> 3) * 1024 + n * 8 + (ch0 & 7)]) = pk;
            } else {
                // temporal: [pos][ch] — fully coalesced
                *reinterpret_cast<ushort4*>(&Oj[(p0 + pos) * 64 + ch0]) = pk;
            }
        }
    }
}

// ---------------------------------------------------------------------------
// Kernel 2: FUSED spatial + temporal attention (one launch, independent work).
// 192 threads.  blockIdx < 2048: temporal block (b,n).
//               blockIdx >= 2048: spatial block (bt, head), threads 0..127 active.
// Both single-pass softmax (temporal keeps max for -inf masking).
// LDS: two 6 KB fp32 buffers, aliased per branch.
// ---------------------------------------------------------------------------
__global__ __launch_bounds__(192) void attn_kernel(
    const unsigned short* __restrict__ qs, const unsigned short* __restrict__ ks,
    const unsigned short* __restrict__ vs,   // spatial [bt][h][n][8]
    const unsigned short* __restrict__ qt, const unsigned short* __restrict__ kt,
    const unsigned short* __restrict__ vt,   // temporal [pos][ch]
    const int* __restrict__ kpm,
    unsigned short* __restrict__ HS, unsigned short* __restrict__ HT)
{
    __shared__ __align__(16) float shA[TT * 64];   // 6 KB
    __shared__ __align__(16) float shB[TT * 64];   // 6 KB
    const int tid = threadIdx.x;
    const float scale = 0.35355339059327373f;      // 1/sqrt(8)

    if (blockIdx.x < 2048) {
        // ================= temporal attention: block = (b, n) =================
        const int n = blockIdx.x & (NN - 1);
        const int b = blockIdx.x >> 7;
        float (*kk)[64] = reinterpret_cast<float(*)[64]>(shA);
        float (*vv)[64] = reinterpret_cast<float(*)[64]>(shB);

        {   // staging: thread = (head hs, time j); 128B-contiguous per j
            const int hs = tid / TT;
            const int j  = tid % TT;
            const long g = (((long)(b * TT + j)) * NN + n) * 64 + hs * 8;
            uint4 ku = *reinterpret_cast<const uint4*>(&kt[g]);
            uint4 vu = *reinterpret_cast<const uint4*>(&vt[g]);
            float kf[8], vf[8];
            unpack8(ku, kf); unpack8(vu, vf);
            #pragma unroll
            for (int d = 0; d < 8; ++d) { kk[j][hs * 8 + d] = kf[d]; vv[j][hs * 8 + d] = vf[d]; }
        }

        const int h = tid / TT;
        const int i = tid % TT;
        const long qb = (((long)(b * TT + i)) * NN + n) * 64 + h * 8;
        float q[8];
        {
            uint4 qu = *reinterpret_cast<const uint4*>(&qt[qb]);
            unpack8(qu, q);
        }
        __syncthreads();

        const int kp = kpm[b];
        float s[TT];
        #pragma unroll
        for (int j = 0; j < TT; ++j) {
            float t = 0.0f;
            #pragma unroll
            for (int d = 0; d < 8; ++d) t = fmaf(q[d], kk[j][h * 8 + d], t);
            s[j] = (j <= i && j < kp) ? t * scale : -INFINITY;
        }
        float mx = -INFINITY;
        #pragma unroll
        for (int j = 0; j < TT; ++j) mx = fmaxf(mx, s[j]);

        float sum = 0.0f;
        float acc[8];
        #pragma unroll
        for (int d = 0; d < 8; ++d) acc[d] = 0.0f;
        #pragma unroll
        for (int j = 0; j < TT; ++j) {
            const float e = __expf(s[j] - mx);  // masked -> exp(-inf)=0
            sum += e;
            #pragma unroll
            for (int d = 0; d < 8; ++d) acc[d] = fmaf(e, vv[j][h * 8 + d], acc[d]);
        }
        const float inv = 1.0f / sum;
        float o[8];
        #pragma unroll
        for (int d = 0; d < 8; ++d) o[d] = acc[d] * inv;
        *reinterpret_cast<uint4*>(&HT[qb]) = pack8(o);
    } else {
        // ================= spatial attention: block = (bt, head) =============
        const int sb = blockIdx.x - 2048;
        const int h  = sb & 7;
        const int bt = sb >> 3;
        const long base = (long)bt * 8192 + h * 1024;
        float (*kf)[8] = reinterpret_cast<float(*)[8]>(shA);
        float (*vf)[8] = reinterpret_cast<float(*)[8]>(shB);

        float q[8];
        if (tid < 128) {
            const uint4 ku = *reinterpret_cast<const uint4*>(&ks[base + tid * 8]);
            const uint4 vu = *reinterpret_cast<const uint4*>(&vs[base + tid * 8]);
            float kk8[8], vv8[8];
            unpack8(ku, kk8); unpack8(vu, vv8);
            #pragma unroll
            for (int d = 0; d < 8; ++d) { kf[tid][d] = kk8[d] * scale; vf[tid][d] = vv8[d]; }
            const uint4 qu = *reinterpret_cast<const uint4*>(&qs[base + tid * 8]);
            unpack8(qu, q);
        }
        __syncthreads();
        if (tid < 128) {
            float sum = 0.f;
            float acc[8];
            #pragma unroll
            for (int d = 0; d < 8; ++d) acc[d] = 0.f;

            for (int m = 0; m < NN; ++m) {
                const float4 ka = *reinterpret_cast<const float4*>(&kf[m][0]);
                const float4 kb = *reinterpret_cast<const float4*>(&kf[m][4]);
                const float4 va = *reinterpret_cast<const float4*>(&vf[m][0]);
                const float4 vb = *reinterpret_cast<const float4*>(&vf[m][4]);
                float s = q[0] * ka.x;
                s = fmaf(q[1], ka.y, s); s = fmaf(q[2], ka.z, s); s = fmaf(q[3], ka.w, s);
                s = fmaf(q[4], kb.x, s); s = fmaf(q[5], kb.y, s);
                s = fmaf(q[6], kb.z, s); s = fmaf(q[7], kb.w, s);
                const float e = __expf(s);   // inputs relu'd: no overflow risk
                sum += e;
                acc[0] = fmaf(e, va.x, acc[0]); acc[1] = fmaf(e, va.y, acc[1]);
                acc[2] = fmaf(e, va.z, acc[2]); acc[3] = fmaf(e, va.w, acc[3]);
                acc[4] = fmaf(e, vb.x, acc[4]); acc[5] = fmaf(e, vb.y, acc[5]);
                acc[6] = fmaf(e, vb.z, acc[6]); acc[7] = fmaf(e, vb.w, acc[7]);
            }
            const float inv = 1.0f / sum;
            float o[8];
            #pragma unroll
            for (int d = 0; d < 8; ++d) o[d] = acc[d] * inv;
            *reinterpret_cast<uint4*>(&HS[((long)bt * NN + tid) * 64 + h * 8]) = pack8(o);
        }
    }
}

// ---------------------------------------------------------------------------
// Kernel 3: epilogue via bf16 MFMA, swapped operands.
// Block = 256 thr (4 waves), 64-position tile.  Grid = PTOT/64 = 768.
// ---------------------------------------------------------------------------
__global__ __launch_bounds__(256) void epi_kernel(
    const float* __restrict__ X,
    const unsigned short* __restrict__ HSb, const unsigned short* __restrict__ HTb,
    const unsigned short* __restrict__ Wt8,  // [8][64][64] bf16
    const float* __restrict__ sbo1, const float* __restrict__ sbo2,
    const float* __restrict__ tbo1, const float* __restrict__ tbo2,
    const float* __restrict__ bxt,
    const float* __restrict__ bh1, const float* __restrict__ bh2,
    float* __restrict__ out)
{
    constexpr int RS = 72;
    __shared__ __align__(16) unsigned short bufA[64][RS], bufB[64][RS], bufC[64][RS];
    const int tid = threadIdx.x;
    const long p0 = (long)blockIdx.x * 64;
    const int w = tid >> 6, l = tid & 63, quad = l >> 4, l16 = l & 15;
    const int chBase = w * 16 + quad * 4;

    #pragma unroll
    for (int i = 0; i < 4; ++i) {
        const int idx = tid + i * 256;      // < 1024
        const int m = idx >> 4;
        const int c = (idx & 15) * 4;
        *reinterpret_cast<ushort4*>(&bufA[m][c]) =
            *reinterpret_cast<const ushort4*>(&HSb[(p0 + m) * 64 + c]);
        *reinterpret_cast<ushort4*>(&bufC[m][c]) =
            *reinterpret_cast<const ushort4*>(&HTb[(p0 + m) * 64 + c]);
    }
    __syncthreads();

    auto gemm = [&](const unsigned short (*in)[RS], int mat,
                    const float* __restrict__ bias, f32x4* accO) {
        bf16x8 af[2];
        #pragma unroll
        for (int kc = 0; kc < 2; ++kc)
            af[kc] = *reinterpret_cast<const bf16x8*>(
                &Wt8[mat * 4096 + (w * 16 + l16) * 64 + kc * 32 + quad * 8]);
        const float4 b4 = *reinterpret_cast<const float4*>(&bias[chBase]);
        #pragma unroll
        for (int pt = 0; pt < 4; ++pt) {
            f32x4 acc = (f32x4){0.f, 0.f, 0.f, 0.f};
            #pragma unroll
            for (int kc = 0; kc < 2; ++kc) {
                bf16x8 bf = *reinterpret_cast<const bf16x8*>(
                    &in[pt * 16 + l16][kc * 32 + quad * 8]);
                acc = __builtin_amdgcn_mfma_f32_16x16x32_bf16(af[kc], bf, acc, 0, 0, 0);
            }
            acc[0] += b4.x; acc[1] += b4.y; acc[2] += b4.z; acc[3] += b4.w;
            accO[pt] = acc;
        }
    };

    auto writeBuf = [&](unsigned short (*dst)[RS], const f32x4* v, bool relu) {
        #pragma unroll
        for (int pt = 0; pt < 4; ++pt) {
            float a0 = v[pt][0], a1 = v[pt][1], a2 = v[pt][2], a3 = v[pt][3];
            if (relu) { a0 = fmaxf(a0, 0.f); a1 = fmaxf(a1, 0.f);
                        a2 = fmaxf(a2, 0.f); a3 = fmaxf(a3, 0.f); }
            ushort4 pk; pk.x = f2bf(a0); pk.y = f2bf(a1); pk.z = f2bf(a2); pk.w = f2bf(a3);
            *reinterpret_cast<ushort4*>(&dst[pt * 16 + l16][chBase]) = pk;
        }
    };

    f32x4 t[4], HSr[4], HTr[4];

    gemm(bufA, 0, sbo1, t);                 // HS1 = relu(HS@sWo1+b)
    __syncthreads();
    writeBuf(bufB, t, true);
    __syncthreads();

    gemm(bufB, 1, sbo2, HSr);               // HS2 (fp32 regs)
    __syncthreads();
    writeBuf(bufA, HSr, false);
    __syncthreads();

    gemm(bufC, 2, tbo1, t);                 // HT1 = relu(HT@tWo1+b)
    __syncthreads();
    writeBuf(bufB, t, true);
    __syncthreads();

    gemm(bufB, 3, tbo2, HTr);               // HT2 (fp32 regs)
    __syncthreads();
    writeBuf(bufC, HTr, false);
    __syncthreads();

    // ---- gate ----
    {
        bf16x8 afS[2], afT[2];
        #pragma unroll
        for (int kc = 0; kc < 2; ++kc) {
            afS[kc] = *reinterpret_cast<const bf16x8*>(
                &Wt8[4 * 4096 + (w * 16 + l16) * 64 + kc * 32 + quad * 8]);
            afT[kc] = *reinterpret_cast<const bf16x8*>(
                &Wt8[5 * 4096 + (w * 16 + l16) * 64 + kc * 32 + quad * 8]);
        }
        const float4 b4 = *reinterpret_cast<const float4*>(&bxt[chBase]);
        #pragma unroll
        for (int pt = 0; pt < 4; ++pt) {
            f32x4 acc = (f32x4){0.f, 0.f, 0.f, 0.f};
            #pragma unroll
            for (int kc = 0; kc < 2; ++kc) {
                bf16x8 hsf = *reinterpret_cast<const bf16x8*>(
                    &bufA[pt * 16 + l16][kc * 32 + quad * 8]);
                acc = __builtin_amdgcn_mfma_f32_16x16x32_bf16(afS[kc], hsf, acc, 0, 0, 0);
            }
            #pragma unroll
            for (int kc = 0; kc < 2; ++kc) {
                bf16x8 htf = *reinterpret_cast<const bf16x8*>(
                    &bufC[pt * 16 + l16][kc * 32 + quad * 8]);
                acc = __builtin_amdgcn_mfma_f32_16x16x32_bf16(afT[kc], htf, acc, 0, 0, 0);
            }
            const float zb[4] = {acc[0] + b4.x, acc[1] + b4.y, acc[2] + b4.z, acc[3] + b4.w};
            f32x4 h;
            #pragma unroll
            for (int r = 0; r < 4; ++r) {
                const float z = 1.0f / (1.0f + __expf(-zb[r]));
                h[r] = z * HSr[pt][r] + (1.0f - z) * HTr[pt][r];
            }
            t[pt] = h;
        }
    }
    __syncthreads();
    writeBuf(bufB, t, false);
    __syncthreads();

    gemm(bufB, 6, bh1, t);                  // H1 = relu(H@Wh1+b)
    __syncthreads();
    writeBuf(bufA, t, true);
    __syncthreads();

    gemm(bufA, 7, bh2, t);                  // out = X + H1@Wh2+b
    #pragma unroll
    for (int pt = 0; pt < 4; ++pt) {
        const long pos = p0 + pt * 16 + l16;
        const float4 xv = *reinterpret_cast<const float4*>(&X[pos * 64 + chBase]);
        float4 o;
        o.x = t[pt][0] + xv.x; o.y = t[pt][1] + xv.y;
        o.z = t[pt][2] + xv.z; o.w = t[pt][3] + xv.w;
        *reinterpret_cast<float4*>(&out[pos * 64 + chBase]) = o;
    }
}

// ---------------------------------------------------------------------------
extern "C" void kernel_launch(void* const* d_in, const int* in_sizes, int n_in,
                              void* d_out, int out_size, void* d_ws, size_t ws_size,
                              hipStream_t stream) {
    const float* X   = (const float*)d_in[0];
    const float* TLE = (const float*)d_in[1];
    const int* kpm   = (const int*)d_in[2];

    const float* sa_Wq = (const float*)d_in[3];  const float* sa_bq = (const float*)d_in[4];
    const float* sa_Wk = (const float*)d_in[5];  const float* sa_bk = (const float*)d_in[6];
    const float* sa_Wv = (const float*)d_in[7];  const float* sa_bv = (const float*)d_in[8];
    const float* sa_Wo1 = (const float*)d_in[9];  const float* sa_bo1 = (const float*)d_in[10];
    const float* sa_Wo2 = (const float*)d_in[11]; const float* sa_bo2 = (const float*)d_in[12];
    const float* ta_Wq = (const float*)d_in[13]; const float* ta_bq = (const float*)d_in[14];
    const float* ta_Wk = (const float*)d_in[15]; const float* ta_bk = (const float*)d_in[16];
    const float* ta_Wv = (const float*)d_in[17]; const float* ta_bv = (const float*)d_in[18];
    const float* ta_Wo1 = (const float*)d_in[19]; const float* ta_bo1 = (const float*)d_in[20];
    const float* ta_Wo2 = (const float*)d_in[21]; const float* ta_bo2 = (const float*)d_in[22];
    const float* g_Wxs = (const float*)d_in[23];
    const float* g_Wxt = (const float*)d_in[24]; const float* g_bxt = (const float*)d_in[25];
    const float* g_Wh1 = (const float*)d_in[26]; const float* g_bh1 = (const float*)d_in[27];
    const float* g_Wh2 = (const float*)d_in[28]; const float* g_bh2 = (const float*)d_in[29];

    unsigned short* wsp = (unsigned short*)d_ws;
    unsigned short* qs  = wsp + 0L * P64;   // [bt][h][n][8]
    unsigned short* ks  = wsp + 1L * P64;
    unsigned short* vs  = wsp + 2L * P64;
    unsigned short* qt  = wsp + 3L * P64;   // [pos][ch]
    unsigned short* kt  = wsp + 4L * P64;
    unsigned short* vt  = wsp + 5L * P64;
    unsigned short* HSb = wsp + 6L * P64;   // [pos][ch]
    unsigned short* HTb = wsp + 7L * P64;   // [pos][ch]
    unsigned short* Wt  = wsp + 8L * P64;            // 6*64*192 bf16
    unsigned short* Wt8 = Wt + 6 * 12288;            // 8*64*64 bf16

    float* out = (float*)d_out;

    hipLaunchKernelGGL(wprep_all, dim3(416), dim3(256), 0, stream,
                       sa_Wq, sa_Wk, sa_Wv, ta_Wq, ta_Wk, ta_Wv,
                       sa_Wo1, sa_Wo2, ta_Wo1, ta_Wo2, g_Wxs, g_Wxt, g_Wh1, g_Wh2,
                       Wt, Wt8);

    hipLaunchKernelGGL(proj_kernel, dim3(PTOT / 64), dim3(256), 0, stream,
                       X, TLE, Wt,
                       sa_bq, sa_bk, sa_bv, ta_bq, ta_bk, ta_bv,
                       qs, ks, vs, qt, kt, vt);

    hipLaunchKernelGGL(attn_kernel, dim3(2048 + 3072), dim3(192), 0, stream,
                       qs, ks, vs, qt, kt, vt, kpm, HSb, HTb);

    hipLaunchKernelGGL(epi_kernel, dim3(PTOT / 64), dim3(256), 0, stream,
                       X, HSb, HTb, Wt8,
                       sa_bo1, sa_bo2, ta_bo1, ta_bo2, g_bxt, g_bh1, g_bh2,
                       out);
}